// Round 1
// baseline (230.345 us; speedup 1.0000x reference)
//
#include <hip/hip_runtime.h>
#include <hip/hip_bf16.h>

#define BB 8
#define QQ 64
#define SS 64
#define TT 64
#define HH 8
#define DH 64
#define NHID 512
#define STAT_K 8
#define TOKEN_K 16

typedef short bf16x8 __attribute__((ext_vector_type(8)));
typedef float f32x4 __attribute__((ext_vector_type(4)));

__device__ inline ushort f2bf_rne(float x) {
    union { float f; unsigned u; } v; v.f = x;
    unsigned r = v.u + 0x7fff + ((v.u >> 16) & 1);
    return (ushort)(r >> 16);
}
__device__ inline float bf2f(ushort h) {
    union { unsigned u; float f; } v; v.u = ((unsigned)h) << 16;
    return v.f;
}

// ---------------------------------------------------------------------------
// One fused convert pass. z<6: transpose+split weight z into bf16 hi/lo
// planes (layout hi[n][k], lo[n][k]). z==6: split queries. z==7: split
// stat_keys (no transpose).
// ---------------------------------------------------------------------------
__global__ __launch_bounds__(256) void conv_all(
    const float* w0, const float* w1, const float* w2,
    const float* w3, const float* w4, const float* w5,
    const float* queries, const float* stat_keys,
    ushort* wT, ushort* q_hi, ushort* q_lo, ushort* sk_hi, ushort* sk_lo)
{
    const int z = blockIdx.z;
    if (z < 6) {
        const float* srcs[6] = {w0, w1, w2, w3, w4, w5};
        const float* src = srcs[z];
        ushort* hi = wT + (size_t)z * 524288;
        ushort* lo = hi + 262144;
        __shared__ float t[32][33];
        const int c0 = blockIdx.x * 32, r0 = blockIdx.y * 32;
        const int tx = threadIdx.x & 31, ty = threadIdx.x >> 5;  // ty 0..7
        #pragma unroll
        for (int i = 0; i < 4; ++i)
            t[ty + 8 * i][tx] = src[(r0 + ty + 8 * i) * 512 + c0 + tx];
        __syncthreads();
        #pragma unroll
        for (int i = 0; i < 4; ++i) {
            float x = t[tx][ty + 8 * i];
            ushort h = f2bf_rne(x);
            int o = (c0 + ty + 8 * i) * 512 + r0 + tx;
            hi[o] = h;
            lo[o] = f2bf_rne(x - bf2f(h));
        }
    } else {
        const float* src = (z == 6) ? queries : stat_keys;
        ushort* hi = (z == 6) ? q_hi : sk_hi;
        ushort* lo = (z == 6) ? q_lo : sk_lo;
        int base = (blockIdx.y * 16 + blockIdx.x) * 1024 + threadIdx.x * 4;
        float4 x = *(const float4*)(src + base);
        ushort4 h, l;
        h.x = f2bf_rne(x.x); l.x = f2bf_rne(x.x - bf2f(h.x));
        h.y = f2bf_rne(x.y); l.y = f2bf_rne(x.y - bf2f(h.y));
        h.z = f2bf_rne(x.z); l.z = f2bf_rne(x.z - bf2f(h.z));
        h.w = f2bf_rne(x.w); l.w = f2bf_rne(x.w - bf2f(h.w));
        *(ushort4*)(hi + base) = h;
        *(ushort4*)(lo + base) = l;
    }
}

// ---------------------------------------------------------------------------
// z-batched split-bf16 MFMA GEMM (fp32-equivalent accuracy): 512x512x512.
// z=0: q @ Wq_stat -> q_stat ; z=1: sk @ Wk_stat -> k_stat ;
// z=2: q @ Wq_token -> q_tokf. B given transposed (Bt[N][K] planes).
// ---------------------------------------------------------------------------
__global__ __launch_bounds__(256) void gemm_split3(
    const ushort* __restrict__ q_hi, const ushort* __restrict__ q_lo,
    const ushort* __restrict__ sk_hi, const ushort* __restrict__ sk_lo,
    const ushort* __restrict__ wT,
    float* __restrict__ q_stat, float* __restrict__ k_stat,
    float* __restrict__ q_tokf)
{
    const int z = blockIdx.z;
    const ushort* Ah = (z == 1) ? sk_hi : q_hi;
    const ushort* Al = (z == 1) ? sk_lo : q_lo;
    const ushort* Bh = wT + (size_t)z * 524288;
    const ushort* Bl = Bh + 262144;
    float* C = (z == 0) ? q_stat : (z == 1) ? k_stat : q_tokf;
    const int K = 512, N = 512;

    __shared__ ushort As[2][64][40];
    __shared__ ushort Bs[2][64][40];
    const int tid = threadIdx.x;
    const int row0 = blockIdx.y * 64, col0 = blockIdx.x * 64;
    const int wave = tid >> 6, lane = tid & 63;
    const int wm = wave & 1, wn = wave >> 1;
    const int m16 = lane & 15, quad = lane >> 4;
    const int srow = tid >> 2, schunk = tid & 3;

    f32x4 acc[2][2];
    #pragma unroll
    for (int i = 0; i < 2; ++i)
        #pragma unroll
        for (int j = 0; j < 2; ++j)
            #pragma unroll
            for (int r = 0; r < 4; ++r) acc[i][j][r] = 0.f;

    for (int k0 = 0; k0 < K; k0 += 32) {
        const size_t aoff = (size_t)(row0 + srow) * K + k0 + schunk * 8;
        const size_t boff = (size_t)(col0 + srow) * K + k0 + schunk * 8;
        *(uint4*)&As[0][srow][schunk * 8] = *(const uint4*)(Ah + aoff);
        *(uint4*)&Bs[0][srow][schunk * 8] = *(const uint4*)(Bh + boff);
        *(uint4*)&As[1][srow][schunk * 8] = *(const uint4*)(Al + aoff);
        *(uint4*)&Bs[1][srow][schunk * 8] = *(const uint4*)(Bl + boff);
        __syncthreads();

        bf16x8 af[2], bf[2], afl[2], bfl[2];
        #pragma unroll
        for (int i = 0; i < 2; ++i) {
            af[i]  = *(const bf16x8*)&As[0][wm * 32 + i * 16 + m16][quad * 8];
            bf[i]  = *(const bf16x8*)&Bs[0][wn * 32 + i * 16 + m16][quad * 8];
            afl[i] = *(const bf16x8*)&As[1][wm * 32 + i * 16 + m16][quad * 8];
            bfl[i] = *(const bf16x8*)&Bs[1][wn * 32 + i * 16 + m16][quad * 8];
        }
        #pragma unroll
        for (int i = 0; i < 2; ++i)
            #pragma unroll
            for (int j = 0; j < 2; ++j) {
                acc[i][j] = __builtin_amdgcn_mfma_f32_16x16x32_bf16(af[i], bf[j], acc[i][j], 0, 0, 0);
                acc[i][j] = __builtin_amdgcn_mfma_f32_16x16x32_bf16(af[i], bfl[j], acc[i][j], 0, 0, 0);
                acc[i][j] = __builtin_amdgcn_mfma_f32_16x16x32_bf16(afl[i], bf[j], acc[i][j], 0, 0, 0);
            }
        __syncthreads();
    }

    #pragma unroll
    for (int i = 0; i < 2; ++i)
        #pragma unroll
        for (int j = 0; j < 2; ++j) {
            int r0 = row0 + wm * 32 + i * 16 + quad * 4;
            int c = col0 + wn * 32 + j * 16 + m16;
            #pragma unroll
            for (int reg = 0; reg < 4; ++reg)
                C[(size_t)(r0 + reg) * N + c] = acc[i][j][reg];
        }
}

// ---------------------------------------------------------------------------
// Final split GEMM: out = ctx(hi/lo) @ Wo(hi/lo), 512x512x512 -> fp32.
// ---------------------------------------------------------------------------
__global__ __launch_bounds__(256) void gemm_out(
    const ushort* __restrict__ Ah, const ushort* __restrict__ Al,
    const ushort* __restrict__ Bh, const ushort* __restrict__ Bl,
    float* __restrict__ C)
{
    const int K = 512, N = 512;
    __shared__ ushort As[2][64][40];
    __shared__ ushort Bs[2][64][40];
    const int tid = threadIdx.x;
    const int row0 = blockIdx.y * 64, col0 = blockIdx.x * 64;
    const int wave = tid >> 6, lane = tid & 63;
    const int wm = wave & 1, wn = wave >> 1;
    const int m16 = lane & 15, quad = lane >> 4;
    const int srow = tid >> 2, schunk = tid & 3;

    f32x4 acc[2][2];
    #pragma unroll
    for (int i = 0; i < 2; ++i)
        #pragma unroll
        for (int j = 0; j < 2; ++j)
            #pragma unroll
            for (int r = 0; r < 4; ++r) acc[i][j][r] = 0.f;

    for (int k0 = 0; k0 < K; k0 += 32) {
        const size_t aoff = (size_t)(row0 + srow) * K + k0 + schunk * 8;
        const size_t boff = (size_t)(col0 + srow) * K + k0 + schunk * 8;
        *(uint4*)&As[0][srow][schunk * 8] = *(const uint4*)(Ah + aoff);
        *(uint4*)&Bs[0][srow][schunk * 8] = *(const uint4*)(Bh + boff);
        *(uint4*)&As[1][srow][schunk * 8] = *(const uint4*)(Al + aoff);
        *(uint4*)&Bs[1][srow][schunk * 8] = *(const uint4*)(Bl + boff);
        __syncthreads();

        bf16x8 af[2], bf[2], afl[2], bfl[2];
        #pragma unroll
        for (int i = 0; i < 2; ++i) {
            af[i]  = *(const bf16x8*)&As[0][wm * 32 + i * 16 + m16][quad * 8];
            bf[i]  = *(const bf16x8*)&Bs[0][wn * 32 + i * 16 + m16][quad * 8];
            afl[i] = *(const bf16x8*)&As[1][wm * 32 + i * 16 + m16][quad * 8];
            bfl[i] = *(const bf16x8*)&Bs[1][wn * 32 + i * 16 + m16][quad * 8];
        }
        #pragma unroll
        for (int i = 0; i < 2; ++i)
            #pragma unroll
            for (int j = 0; j < 2; ++j) {
                acc[i][j] = __builtin_amdgcn_mfma_f32_16x16x32_bf16(af[i], bf[j], acc[i][j], 0, 0, 0);
                acc[i][j] = __builtin_amdgcn_mfma_f32_16x16x32_bf16(af[i], bfl[j], acc[i][j], 0, 0, 0);
                acc[i][j] = __builtin_amdgcn_mfma_f32_16x16x32_bf16(afl[i], bf[j], acc[i][j], 0, 0, 0);
            }
        __syncthreads();
    }

    #pragma unroll
    for (int i = 0; i < 2; ++i)
        #pragma unroll
        for (int j = 0; j < 2; ++j) {
            int r0 = row0 + wm * 32 + i * 16 + quad * 4;
            int c = col0 + wn * 32 + j * 16 + m16;
            #pragma unroll
            for (int reg = 0; reg < 4; ++reg)
                C[(size_t)(r0 + reg) * N + c] = acc[i][j][reg];
        }
}

// ---------------------------------------------------------------------------
// Token projections: 64x256 block tile. A rows map to last-16-token slices:
// GEMM row r -> global row (r>>4)*64 + 48 + (r&15).
// z=0: token_keys @ Wk_token -> k_tok (row-major [8192][512] bf16)
// z=1: values @ Wv -> v_projT   (per-head transposed: [bh=64][d=64][st=1024])
// ---------------------------------------------------------------------------
__global__ __launch_bounds__(256) void gemm_tok(
    const float* __restrict__ token_keys, const float* __restrict__ values,
    const ushort* __restrict__ wkt_h, const ushort* __restrict__ wv_h,
    ushort* __restrict__ k_tok, ushort* __restrict__ v_projT)
{
    const int z = blockIdx.z;
    const float* A = z ? values : token_keys;
    const ushort* Bh = z ? wv_h : wkt_h;
    const int K = 512, N = 512;

    __shared__ ushort As[64][40];
    __shared__ ushort Bs[256][40];
    const int tid = threadIdx.x;
    const int row0 = blockIdx.y * 64, col0 = blockIdx.x * 256;
    const int wave = tid >> 6, lane = tid & 63;
    const int m16 = lane & 15, quad = lane >> 4;
    const int srow = tid >> 2, schunk = tid & 3;   // A staging: 64 rows x 4 chunks

    // A global row for this thread's staging row
    const int r = row0 + srow;
    const size_t arow = (size_t)((r >> 4) * 64 + 48 + (r & 15)) * K;

    f32x4 acc[4][4];
    #pragma unroll
    for (int i = 0; i < 4; ++i)
        #pragma unroll
        for (int j = 0; j < 4; ++j)
            #pragma unroll
            for (int rr = 0; rr < 4; ++rr) acc[i][j][rr] = 0.f;

    for (int k0 = 0; k0 < K; k0 += 32) {
        // --- stage A: 64x32 fp32 -> bf16. thread: 2 float4 -> 1 ds_write_b128
        const float* ap = A + arow + k0 + schunk * 8;
        float4 x0 = ((const float4*)ap)[0];
        float4 x1 = ((const float4*)ap)[1];
        ushort4 h0, h1;
        h0.x = f2bf_rne(x0.x); h0.y = f2bf_rne(x0.y);
        h0.z = f2bf_rne(x0.z); h0.w = f2bf_rne(x0.w);
        h1.x = f2bf_rne(x1.x); h1.y = f2bf_rne(x1.y);
        h1.z = f2bf_rne(x1.z); h1.w = f2bf_rne(x1.w);
        *(ushort4*)&As[srow][schunk * 8] = h0;
        *(ushort4*)&As[srow][schunk * 8 + 4] = h1;
        // --- stage B: 256x32 bf16, 4 uint4/thread
        #pragma unroll
        for (int i = 0; i < 4; ++i) {
            int v = tid + i * 256;
            int brow = v >> 2, bchunk = v & 3;
            *(uint4*)&Bs[brow][bchunk * 8] =
                *(const uint4*)(Bh + (size_t)(col0 + brow) * K + k0 + bchunk * 8);
        }
        __syncthreads();

        bf16x8 af[4], bf[4];
        #pragma unroll
        for (int i = 0; i < 4; ++i) {
            af[i] = *(const bf16x8*)&As[i * 16 + m16][quad * 8];
            bf[i] = *(const bf16x8*)&Bs[wave * 64 + i * 16 + m16][quad * 8];
        }
        #pragma unroll
        for (int i = 0; i < 4; ++i)
            #pragma unroll
            for (int j = 0; j < 4; ++j)
                acc[i][j] = __builtin_amdgcn_mfma_f32_16x16x32_bf16(af[i], bf[j], acc[i][j], 0, 0, 0);
        __syncthreads();
    }

    #pragma unroll
    for (int i = 0; i < 4; ++i)
        #pragma unroll
        for (int j = 0; j < 4; ++j) {
            int rg = row0 + i * 16 + quad * 4;
            int c = col0 + wave * 64 + j * 16 + m16;
            if (z == 0) {
                #pragma unroll
                for (int reg = 0; reg < 4; ++reg)
                    k_tok[(size_t)(rg + reg) * N + c] = f2bf_rne(acc[i][j][reg]);
            } else {
                // transpose into [ (b*8+h)*64 + d ][ st ], st = rg&1023 (4-aligned)
                int bb = rg >> 10, st = rg & 1023;
                int hh = c >> 6, dd = c & 63;
                ushort4 o4;
                o4.x = f2bf_rne(acc[i][j][0]);
                o4.y = f2bf_rne(acc[i][j][1]);
                o4.z = f2bf_rne(acc[i][j][2]);
                o4.w = f2bf_rne(acc[i][j][3]);
                *(ushort4*)(v_projT + (((size_t)((bb * 8 + hh) * 64 + dd)) << 10) + st) = o4;
            }
        }
}

// ---------------------------------------------------------------------------
// Stat scores + valid-len mask + top-8 + softmax -> DENSE stat_w [4096][64]
// (zero at non-selected segments). One wave per (b,h,q).
// ---------------------------------------------------------------------------
__global__ __launch_bounds__(64) void stat_topk(
    const float* __restrict__ q_stat, const float* __restrict__ k_stat,
    const int* __restrict__ valid_lens,
    float* __restrict__ stat_wd)
{
    const int bid = blockIdx.x;           // b*512 + h*64 + q
    const int b = bid >> 9;
    const int hq = bid & 511;
    const int h = hq >> 6;
    const int q = hq & 63;
    const int lane = threadIdx.x;         // segment index s

    __shared__ float sq[64];
    sq[lane] = q_stat[(b * QQ + q) * NHID + h * DH + lane];
    __syncthreads();

    const float4* kr = (const float4*)(k_stat + (b * SS + lane) * NHID + h * DH);
    const float4* sq4 = (const float4*)sq;
    float sc = 0.f;
    #pragma unroll
    for (int i = 0; i < 16; ++i) {
        float4 a = sq4[i], kk = kr[i];
        sc += a.x * kk.x + a.y * kk.y + a.z * kk.z + a.w * kk.w;
    }
    sc *= 0.125f;
    if (lane >= valid_lens[b]) sc = -1e6f;

    const float sc_keep = sc;
    float my = sc;
    bool picked = false;
    float m0 = 0.f, den = 0.f;
    #pragma unroll
    for (int j = 0; j < STAT_K; ++j) {
        float v = my;
        int idx = lane;
        #pragma unroll
        for (int off = 32; off > 0; off >>= 1) {
            float ov = __shfl_down(v, off);
            int   oi = __shfl_down(idx, off);
            if (ov > v || (ov == v && oi < idx)) { v = ov; idx = oi; }
        }
        v = __shfl(v, 0);
        idx = __shfl(idx, 0);
        if (j == 0) m0 = v;
        den += __expf(v - m0);
        if (lane == idx) { my = -3e38f; picked = true; }
    }
    float w_out = picked ? __expf(sc_keep - m0) / den : 0.f;
    stat_wd[(size_t)bid * 64 + lane] = w_out;
}

// ---------------------------------------------------------------------------
// Dense MFMA token attention. One block per (b,h, 16-q slice); 4 waves.
// Swapped QK: sc[st][q] = mfma(K_frag, Qhi) + mfma(K_frag, Qlo)  (fp32-equiv q)
// -> per-seg softmax over t via 3 in-lane adds + shfl_xor(16,32), fp32 den
// -> comb = stat_w * e/den split into bf16 hi/lo planes in swizzled LDS
// -> PV: out[d][q] = mfma(V^T_frag, comb_hi) + mfma(V^T_frag, comb_lo),
// chunked over 4 groups of 16 segments (K=256 st per chunk).
// Unselected/invalid segments have stat_w == 0 and contribute exactly 0.
// ---------------------------------------------------------------------------
__global__ __launch_bounds__(256) void tok_attend_dense(
    const float* __restrict__ q_tokf, const ushort* __restrict__ k_tok,
    const ushort* __restrict__ v_projT, const float* __restrict__ stat_wd,
    ushort* __restrict__ ctx_hi, ushort* __restrict__ ctx_lo)
{
    const int bid = blockIdx.x;
    const int bh = bid >> 2, qb = bid & 3;
    const int b = bh >> 3, h = bh & 7;
    const int tid = threadIdx.x, wave = tid >> 6, lane = tid & 63;
    const int l15 = lane & 15, g = lane >> 4;
    const int q0 = qb * 16;

    __shared__ ushort qs_hi[16][72], qs_lo[16][72];   // q rows, padded (2-way free)
    __shared__ float  sw[16][65];                     // stat_w, conflict-free
    __shared__ ushort comb_hi[16][264], comb_lo[16][264]; // [q][st], XOR-swizzled

    // ---- stage q slice (fp32 -> hi/lo bf16) and stat_w slice
    {
        const int qq = tid >> 4, c = (tid & 15) * 4;
        float4 x = *(const float4*)(q_tokf + (size_t)(b * 64 + q0 + qq) * 512 + h * 64 + c);
        ushort4 hx, lx;
        hx.x = f2bf_rne(x.x); lx.x = f2bf_rne(x.x - bf2f(hx.x));
        hx.y = f2bf_rne(x.y); lx.y = f2bf_rne(x.y - bf2f(hx.y));
        hx.z = f2bf_rne(x.z); lx.z = f2bf_rne(x.z - bf2f(hx.z));
        hx.w = f2bf_rne(x.w); lx.w = f2bf_rne(x.w - bf2f(hx.w));
        *(ushort4*)&qs_hi[qq][c] = hx;
        *(ushort4*)&qs_lo[qq][c] = lx;
        float4 y = *(const float4*)(stat_wd + (size_t)bh * 4096 + (q0 + qq) * 64 + c);
        sw[qq][c] = y.x; sw[qq][c + 1] = y.y; sw[qq][c + 2] = y.z; sw[qq][c + 3] = y.w;
    }
    __syncthreads();

    f32x4 accd;                                       // [16 d] x [16 q] tile
    #pragma unroll
    for (int rr = 0; rr < 4; ++rr) accd[rr] = 0.f;

    const int swz = (l15 & 7) << 4;                   // per-q-row byte XOR key

    for (int ch = 0; ch < 4; ++ch) {
        // ---- QK: this wave computes 4 segments (64 st) x 16 q
        const int sbase = ch * 16 + wave * 4;
        f32x4 sc[4];
        #pragma unroll
        for (int mt = 0; mt < 4; ++mt)
            #pragma unroll
            for (int rr = 0; rr < 4; ++rr) sc[mt][rr] = 0.f;

        #pragma unroll
        for (int ks = 0; ks < 2; ++ks) {
            bf16x8 bhf = *(const bf16x8*)&qs_hi[l15][ks * 32 + g * 8];
            bf16x8 blf = *(const bf16x8*)&qs_lo[l15][ks * 32 + g * 8];
            #pragma unroll
            for (int mt = 0; mt < 4; ++mt) {
                const ushort* kp = k_tok +
                    (size_t)(b * 1024 + (sbase + mt) * 16 + l15) * 512 + h * 64 + ks * 32 + g * 8;
                bf16x8 a = *(const bf16x8*)kp;
                sc[mt] = __builtin_amdgcn_mfma_f32_16x16x32_bf16(a, bhf, sc[mt], 0, 0, 0);
                sc[mt] = __builtin_amdgcn_mfma_f32_16x16x32_bf16(a, blf, sc[mt], 0, 0, 0);
            }
        }

        // ---- per-segment softmax over 16 tokens + comb write (hi/lo)
        #pragma unroll
        for (int mt = 0; mt < 4; ++mt) {
            float e0 = __expf(sc[mt][0] * 0.125f);
            float e1 = __expf(sc[mt][1] * 0.125f);
            float e2 = __expf(sc[mt][2] * 0.125f);
            float e3 = __expf(sc[mt][3] * 0.125f);
            float den = e0 + e1 + e2 + e3;
            den += __shfl_xor(den, 16);
            den += __shfl_xor(den, 32);
            float scl = sw[l15][sbase + mt] / den;
            ushort4 hx, lx;
            float c0 = e0 * scl; hx.x = f2bf_rne(c0); lx.x = f2bf_rne(c0 - bf2f(hx.x));
            float c1 = e1 * scl; hx.y = f2bf_rne(c1); lx.y = f2bf_rne(c1 - bf2f(hx.y));
            float c2 = e2 * scl; hx.z = f2bf_rne(c2); lx.z = f2bf_rne(c2 - bf2f(hx.z));
            float c3 = e3 * scl; hx.w = f2bf_rne(c3); lx.w = f2bf_rne(c3 - bf2f(hx.w));
            int colb = (((wave * 4 + mt) * 16 + g * 4) * 2) ^ swz;
            *(ushort4*)((char*)&comb_hi[l15][0] + colb) = hx;
            *(ushort4*)((char*)&comb_lo[l15][0] + colb) = lx;
        }
        __syncthreads();

        // ---- PV over this chunk (K = 256 st); wave owns 16-d block
        #pragma unroll
        for (int ks = 0; ks < 8; ++ks) {
            const ushort* vp = v_projT +
                ((size_t)(bh * 64 + wave * 16 + l15) << 10) + ch * 256 + ks * 32 + g * 8;
            bf16x8 a = *(const bf16x8*)vp;
            int colb = ((ks * 32 + g * 8) * 2) ^ swz;
            bf16x8 bhf = *(const bf16x8*)((const char*)&comb_hi[l15][0] + colb);
            bf16x8 blf = *(const bf16x8*)((const char*)&comb_lo[l15][0] + colb);
            accd = __builtin_amdgcn_mfma_f32_16x16x32_bf16(a, bhf, accd, 0, 0, 0);
            accd = __builtin_amdgcn_mfma_f32_16x16x32_bf16(a, blf, accd, 0, 0, 0);
        }
        __syncthreads();
    }

    // ---- epilogue: lane holds d = wave*16 + g*4 + r, q = q0 + l15
    {
        size_t o = (size_t)(b * 64 + q0 + l15) * 512 + h * 64 + wave * 16 + g * 4;
        ushort4 hx, lx;
        #pragma unroll
        for (int rr = 0; rr < 4; ++rr) {
            ushort hh2 = f2bf_rne(accd[rr]);
            ((ushort*)&hx)[rr] = hh2;
            ((ushort*)&lx)[rr] = f2bf_rne(accd[rr] - bf2f(hh2));
        }
        *(ushort4*)(ctx_hi + o) = hx;
        *(ushort4*)(ctx_lo + o) = lx;
    }
}

extern "C" void kernel_launch(void* const* d_in, const int* in_sizes, int n_in,
                              void* d_out, int out_size, void* d_ws, size_t ws_size,
                              hipStream_t stream) {
    const float* queries    = (const float*)d_in[0];
    const float* stat_keys  = (const float*)d_in[1];
    const float* token_keys = (const float*)d_in[2];
    const float* values     = (const float*)d_in[3];
    const int*   valid_lens = (const int*)d_in[4];
    const float* Wq_stat    = (const float*)d_in[5];
    const float* Wq_token   = (const float*)d_in[6];
    const float* Wk_stat    = (const float*)d_in[7];
    const float* Wk_token   = (const float*)d_in[8];
    const float* Wv         = (const float*)d_in[9];
    const float* Wo         = (const float*)d_in[10];

    char* w = (char*)d_ws;
    ushort* wT      = (ushort*)(w + 0);          // 6 x (hi+lo) x 262144 ush
    ushort* q_hi    = (ushort*)(w + 6291456);
    ushort* q_lo    = q_hi + 262144;
    ushort* sk_hi   = (ushort*)(w + 7340032);
    ushort* sk_lo   = sk_hi + 262144;
    float*  q_stat  = (float*)(w + 8388608);
    float*  k_stat  = (float*)(w + 9437184);
    float*  q_tokf  = (float*)(w + 10485760);
    ushort* k_tok   = (ushort*)(w + 11534336);   // bf16 [8192][512]
    ushort* v_projT = (ushort*)(w + 19922944);   // bf16 [64 bh][64 d][1024 st]
    ushort* ctx_hi  = (ushort*)(w + 28311552);
    ushort* ctx_lo  = ctx_hi + 262144;
    float*  stat_wd = (float*)(w + 29360128);    // dense [4096][64]

    // weight order in wT: 0=Wq_stat 1=Wk_stat 2=Wq_token 3=Wk_token 4=Wv 5=Wo
    ushort* wkt_h = wT + 3 * 524288;
    ushort* wv_h  = wT + 4 * 524288;
    ushort* wo_h  = wT + 5 * 524288, *wo_l = wo_h + 262144;

    // 1. all converts (weights transpose+split, queries/stat_keys split)
    conv_all<<<dim3(16, 16, 8), 256, 0, stream>>>(
        Wq_stat, Wk_stat, Wq_token, Wk_token, Wv, Wo,
        queries, stat_keys, wT, q_hi, q_lo, sk_hi, sk_lo);

    // 2. three split-precision projections in one z-batched launch
    gemm_split3<<<dim3(8, 8, 3), 256, 0, stream>>>(
        q_hi, q_lo, sk_hi, sk_lo, wT, q_stat, k_stat, q_tokf);

    // 3. stat top-8 + softmax -> dense stat_w
    stat_topk<<<4096, 64, 0, stream>>>(q_stat, k_stat, valid_lens, stat_wd);

    // 4. token-path projections (k_tok row-major, v transposed per head)
    gemm_tok<<<dim3(2, 128, 2), 256, 0, stream>>>(
        token_keys, values, wkt_h, wv_h, k_tok, v_projT);

    // 5. dense MFMA token attention -> ctx (hi/lo planes)
    tok_attend_dense<<<256, 256, 0, stream>>>(
        q_tokf, k_tok, v_projT, stat_wd, ctx_hi, ctx_lo);

    // 6. output projection
    gemm_out<<<dim3(8, 8), 256, 0, stream>>>(
        ctx_hi, ctx_lo, wo_h, wo_l, (float*)d_out);
}